// Round 16
// baseline (322.989 us; speedup 1.0000x reference)
//
#include <hip/hip_runtime.h>
#include <stdint.h>
#include <stddef.h>

typedef unsigned short u16;
typedef unsigned int u32;
typedef __attribute__((ext_vector_type(8))) short s8v;   // 8 bf16 = one MFMA A/B frag
typedef __attribute__((ext_vector_type(4))) short s4v;
typedef __attribute__((ext_vector_type(4))) float f4v;   // MFMA C/D frag / float4

#define D_MODEL 2048
#define NH 16
#define DK 128

__device__ __forceinline__ float b2f(u16 u) {
    union { u32 i; float f; } v; v.i = ((u32)u) << 16; return v.f;
}
__device__ __forceinline__ u16 f2b(float f) {  // RNE; values here always finite
    u32 u = __builtin_bit_cast(u32, f);
    u32 r = (u + 0x7fffu + ((u >> 16) & 1u)) >> 16;
    return (u16)r;
}
__device__ __forceinline__ float fexp2(float x) {        // native v_exp_f32 (base-2)
    return __builtin_amdgcn_exp2f(x);
}
__device__ __forceinline__ f4v mfma16(s8v a, s8v b, f4v c) {
    return __builtin_amdgcn_mfma_f32_16x16x32_bf16(a, b, c, 0, 0, 0);
}
// async global->LDS, 16B/lane. LDS dest must be the WAVE-UNIFORM base; HW adds lane*16.
__device__ __forceinline__ void gload_lds16(const void* g, void* l) {
    __builtin_amdgcn_global_load_lds(
        (const __attribute__((address_space(1))) u32*)(uintptr_t)g,
        (__attribute__((address_space(3))) u32*)(uintptr_t)l, 16, 0, 0);
}

__device__ __forceinline__ void store_out(u16* p, float v)   { *p = f2b(v); }
__device__ __forceinline__ void store_out(float* p, float v) { *p = v; }

#define SBAR()   asm volatile("s_barrier" ::: "memory")
#define VMCNT(n) asm volatile("s_waitcnt vmcnt(" #n ")" ::: "memory")

// ---------------------------------------------------------------------------
// fp32 -> bf16 conversion pass. grid.y selects segment (0: x, 1..4: weights).
// ---------------------------------------------------------------------------
__global__ __launch_bounds__(256) void cvt_bf16(
    const float* __restrict__ s0, const float* __restrict__ s1,
    const float* __restrict__ s2, const float* __restrict__ s3,
    const float* __restrict__ s4,
    u16* __restrict__ d0, u16* __restrict__ d1, u16* __restrict__ d2,
    u16* __restrict__ d3, u16* __restrict__ d4,
    int n0, int nw)
{
    const int seg = blockIdx.y;
    const float* s = (seg == 0) ? s0 : (seg == 1) ? s1 : (seg == 2) ? s2 : (seg == 3) ? s3 : s4;
    u16*         d = (seg == 0) ? d0 : (seg == 1) ? d1 : (seg == 2) ? d2 : (seg == 3) ? d3 : d4;
    const int    n = (seg == 0) ? n0 : nw;
    int i = (blockIdx.x * 256 + threadIdx.x) * 8;
    if (i >= n) return;
    f4v a = *(const f4v*)(s + i);
    f4v b = *(const f4v*)(s + i + 4);
    s8v o;
    o[0] = (short)f2b(a[0]); o[1] = (short)f2b(a[1]);
    o[2] = (short)f2b(a[2]); o[3] = (short)f2b(a[3]);
    o[4] = (short)f2b(b[0]); o[5] = (short)f2b(b[1]);
    o[6] = (short)f2b(b[2]); o[7] = (short)f2b(b[3]);
    *(s8v*)(d + i) = o;
}

// ---------------------------------------------------------------------------
// RoPE cos/sin table: tab[s*64 + ip] = (cos, sin)(pos[s] * 10000^(-ip/64)).
// ---------------------------------------------------------------------------
__global__ __launch_bounds__(256) void rope_table(
    float2* __restrict__ tab, const int* __restrict__ pos, int S)
{
    int idx = blockIdx.x * 256 + threadIdx.x;
    if (idx >= S * 64) return;
    int s  = idx >> 6;
    int ip = idx & 63;
    float freq = __expf((float)ip * -0.14391156831212787f);  // 10000^(-ip/64)
    float ang  = (float)pos[s] * freq;
    tab[idx] = make_float2(cosf(ang), sinf(ang));
}

// ---------------------------------------------------------------------------
// GEMM 8-phase 256x256 + fused RoPE epilogue — unchanged from round 14.
// ---------------------------------------------------------------------------
__global__ __launch_bounds__(512) void gemm256(
    const u16* __restrict__ A,
    const u16* __restrict__ B0, const u16* __restrict__ B1,
    u16* __restrict__ C0, u16* __restrict__ C1,
    const float2* __restrict__ rtab, int Sdim,
    int M, int N, int K)
{
    const int z = blockIdx.z;
    const u16* Bp = (z == 0) ? B0 : B1;
    u16*       Cp = (z == 0) ? C0 : C1;

    __shared__ short As[2 * 256 * 64];   // 64 KB (2 slots)
    __shared__ short Bs[2 * 256 * 64];   // 64 KB

    const int t    = threadIdx.x;
    const int lane = t & 63;
    const int w    = t >> 6;             // 0..7
    const int wr   = w >> 2;             // 0..1  (128-row band)
    const int wc   = w & 3;              // 0..3  (64-col band)
    const int m0   = blockIdx.x * 256;
    const int n0   = blockIdx.y * 256;

    const int srow = t >> 3;                          // 0..63
    const int scol = (((t & 7) ^ ((t >> 3) & 7)) * 8);

    const u16* gA = A  + (size_t)(m0 + srow) * K + scol;
    const u16* gB = Bp + (size_t)(n0 + srow) * K + scol;
    char* lA = (char*)As + (size_t)w * 1024;          // wave-uniform bases
    char* lB = (char*)Bs + (size_t)w * 1024;
    const size_t rstep = (size_t)64 * K;

    const int fr = lane & 15;
    const int g4 = lane >> 4;
    const int xa = fr & 7;

    f4v acc[8][4];
#pragma unroll
    for (int i = 0; i < 8; i++)
#pragma unroll
        for (int j = 0; j < 4; j++) acc[i][j] = (f4v){0.f, 0.f, 0.f, 0.f};

    auto stageA = [&](int p, int kt, int h) {
        const u16* g = gA + (size_t)kt * 64;
#pragma unroll
        for (int j = 0; j < 2; j++)
            gload_lds16(g + (size_t)(2 * h + j) * rstep,
                        lA + p * 32768 + (2 * h + j) * 8192);
    };
    auto stageB = [&](int p, int kt, int h) {
        const u16* g = gB + (size_t)kt * 64;
#pragma unroll
        for (int j = 0; j < 2; j++)
            gload_lds16(g + (size_t)(2 * h + j) * rstep,
                        lB + p * 32768 + (2 * h + j) * 8192);
    };
    auto loadA = [&](int p, int mh, int ks, s8v* aF) {
        const short* base = As + p * 16384;
        const int sl = ((ks * 4 + g4) ^ xa) * 8;
#pragma unroll
        for (int mi = 0; mi < 4; mi++)
            aF[mi] = *(const s8v*)&base[(wr * 128 + mh * 64 + mi * 16 + fr) * 64 + sl];
    };
    auto loadB = [&](int p, int ks, s8v* bF) {
        const short* base = Bs + p * 16384;
        const int sl = ((ks * 4 + g4) ^ xa) * 8;
#pragma unroll
        for (int ni = 0; ni < 4; ni++)
            bF[ni] = *(const s8v*)&base[(wc * 64 + ni * 16 + fr) * 64 + sl];
    };
    auto mfc = [&](int mh, s8v* aF, s8v* bF) {
        __builtin_amdgcn_s_setprio(1);
#pragma unroll
        for (int mi = 0; mi < 4; mi++)
#pragma unroll
            for (int ni = 0; ni < 4; ni++)
                acc[mh * 4 + mi][ni] = mfma16(aF[mi], bF[ni], acc[mh * 4 + mi][ni]);
        __builtin_amdgcn_s_setprio(0);
    };

    const int NT = K / 64;               // 32
    const int NI = NT / 2;               // 16

    stageB(0, 0, 0); stageB(0, 0, 1); stageA(0, 0, 0); stageA(0, 0, 1);
    stageB(1, 1, 0);
    VMCNT(2);
    SBAR();

    for (int i = 0; i < NI; i++) {
        const int k1 = 2 * i + 1;
        const int k2 = (2 * i + 2 < NT) ? 2 * i + 2 : 0;
        const int k3 = (2 * i + 3 < NT) ? 2 * i + 3 : 1;
        s8v aF[4], bF[4];

        // P1
        loadA(0, 0, 0, aF); loadB(0, 0, bF);
        stageB(1, k1, 1);
        VMCNT(4); SBAR();
        mfc(0, aF, bF);
        SBAR();
        // P2
        loadA(0, 1, 0, aF);
        stageA(1, k1, 0);
        SBAR();
        mfc(1, aF, bF);
        SBAR();
        // P3
        loadA(0, 0, 1, aF); loadB(0, 1, bF);
        stageA(1, k1, 1);
        SBAR();
        mfc(0, aF, bF);
        SBAR();
        // P4 — vmcnt(2): certify A(t1,h1) (P3) for P5-P7
        loadA(0, 1, 1, aF);
        stageB(0, k2, 0);
        VMCNT(2); SBAR();
        mfc(1, aF, bF);
        SBAR();
        // P5
        loadA(1, 0, 0, aF); loadB(1, 0, bF);
        stageB(0, k2, 1);
        VMCNT(4); SBAR();
        mfc(0, aF, bF);
        SBAR();
        // P6
        loadA(1, 1, 0, aF);
        stageA(0, k2, 0);
        SBAR();
        mfc(1, aF, bF);
        SBAR();
        // P7
        loadA(1, 0, 1, aF); loadB(1, 1, bF);
        stageA(0, k2, 1);
        SBAR();
        mfc(0, aF, bF);
        SBAR();
        // P8 — vmcnt(2): certify A(t0+2,h1) (P7) for next P1-P4
        loadA(1, 1, 1, aF);
        stageB(1, k3, 0);
        VMCNT(2); SBAR();
        mfc(1, aF, bF);
        SBAR();
    }
    VMCNT(0);

    // fused-RoPE epilogue
    const int rg = g4 * 4;
    const float scale = (z == 0) ? 0.12751919968793342f : 1.0f;  // log2e/sqrt(128)
    const int srow_b = (m0 % Sdim) + wr * 128;   // 256-row tiles never straddle batch
#pragma unroll
    for (int mit = 0; mit < 8; mit++)
#pragma unroll
        for (int ni = 0; ni < 4; ni++) {
            const int col = n0 + wc * 64 + ni * 16 + fr;
            const int ip  = (col & 127) >> 1;
            const int odd = col & 1;
            size_t base = (size_t)(m0 + wr * 128 + mit * 16 + rg) * N + col;
            const int sr = srow_b + mit * 16 + rg;
#pragma unroll
            for (int r = 0; r < 4; r++) {
                float2 cs = rtab[(size_t)(sr + r) * 64 + ip];
                float v  = acc[mit][ni][r];
                float pv = __shfl_xor(v, 1);                   // partner col^1
                float o  = odd ? (pv * cs.y + v * cs.x)        // e*sin + o*cos
                               : (v * cs.x - pv * cs.y);       // e*cos - o*sin
                Cp[base + (size_t)r * N] = f2b(o * scale);
            }
        }
}

// ---------------------------------------------------------------------------
// GEMM 8-phase 256x128 3-slot — unchanged from round 14 (passed).
// MODE 0: direct store. MODE 1: fused V^T epilogue.
// ---------------------------------------------------------------------------
template<typename OutT, int MODE>
__global__ __launch_bounds__(512) void gemm128(
    const u16* __restrict__ A, const u16* __restrict__ Bp,
    OutT* __restrict__ Cp, int M, int N, int K, int Sdim)
{
    __shared__ short As[3 * 256 * 64];   // 96 KB (3 slots; also V^T staging)
    __shared__ short Bs[3 * 128 * 64];   // 48 KB

    const int t    = threadIdx.x;
    const int lane = t & 63;
    const int w    = t >> 6;
    const int wr   = w >> 1;
    const int wc   = w & 1;
    const int m0   = blockIdx.x * 256;
    const int n0   = blockIdx.y * 128;

    const int srow = t >> 3;
    const int scol = (((t & 7) ^ ((t >> 3) & 7)) * 8);

    const u16* gA = A  + (size_t)(m0 + srow) * K + scol;
    const u16* gB = Bp + (size_t)(n0 + srow) * K + scol;
    char* lA = (char*)As + (size_t)w * 1024;
    char* lB = (char*)Bs + (size_t)w * 1024;
    const size_t rstep = (size_t)64 * K;

    const int fr = lane & 15;
    const int g4 = lane >> 4;
    const int xa = fr & 7;

    f4v acc[4][4];
#pragma unroll
    for (int i = 0; i < 4; i++)
#pragma unroll
        for (int j = 0; j < 4; j++) acc[i][j] = (f4v){0.f, 0.f, 0.f, 0.f};

    auto stageA = [&](int p, int kt, int h) {
        const u16* g = gA + (size_t)kt * 64;
#pragma unroll
        for (int j = 0; j < 2; j++)
            gload_lds16(g + (size_t)(2 * h + j) * rstep,
                        lA + p * 32768 + (2 * h + j) * 8192);
    };
    auto stageB = [&](int p, int kt) {
        const u16* g = gB + (size_t)kt * 64;
#pragma unroll
        for (int j = 0; j < 2; j++)
            gload_lds16(g + (size_t)j * rstep,
                        lB + p * 16384 + j * 8192);
    };
    auto loadA = [&](int p, int mh, int ks, s8v* aF) {
        const short* base = As + p * 16384;
        const int sl = ((ks * 4 + g4) ^ xa) * 8;
#pragma unroll
        for (int j = 0; j < 2; j++)
            aF[j] = *(const s8v*)&base[(wr * 64 + (mh * 2 + j) * 16 + fr) * 64 + sl];
    };
    auto loadB = [&](int p, int ks, s8v* bF) {
        const short* base = Bs + p * 8192;
        const int sl = ((ks * 4 + g4) ^ xa) * 8;
#pragma unroll
        for (int ni = 0; ni < 4; ni++)
            bF[ni] = *(const s8v*)&base[(wc * 64 + ni * 16 + fr) * 64 + sl];
    };
    auto mfc = [&](int mh, s8v* aF, s8v* bF) {
        __builtin_amdgcn_s_setprio(1);
#pragma unroll
        for (int j = 0; j < 2; j++)
#pragma unroll
            for (int ni = 0; ni < 4; ni++)
                acc[mh * 2 + j][ni] = mfma16(aF[j], bF[ni], acc[mh * 2 + j][ni]);
        __builtin_amdgcn_s_setprio(0);
    };

    const int NT = K / 64;
    const int NI = NT / 2;

    stageA(0, 0, 0); stageA(0, 0, 1); stageB(0, 0);
    stageA(1, 1, 0); stageA(1, 1, 1); stageB(1, 1);
    VMCNT(6);
    SBAR();

    int s0 = 0, s1 = 1, s2 = 2;
    for (int i = 0; i < NI; i++) {
        const int k2 = (2 * i + 2 < NT) ? 2 * i + 2 : 0;
        const int k3 = (2 * i + 3 < NT) ? 2 * i + 3 : 1;
        s8v aF[2], bF[4];

        loadB(s0, 0, bF); loadA(s0, 0, 0, aF);
        stageA(s2, k2, 0);
        SBAR(); mfc(0, aF, bF); SBAR();
        loadA(s0, 1, 0, aF);
        stageA(s2, k2, 1);
        SBAR(); mfc(1, aF, bF); SBAR();
        loadB(s0, 1, bF); loadA(s0, 0, 1, aF);
        stageB(s2, k2);
        SBAR(); mfc(0, aF, bF); SBAR();
        loadA(s0, 1, 1, aF);
        VMCNT(6); SBAR(); mfc(1, aF, bF); SBAR();
        loadB(s1, 0, bF); loadA(s1, 0, 0, aF);
        stageA(s0, k3, 0);
        SBAR(); mfc(0, aF, bF); SBAR();
        loadA(s1, 1, 0, aF);
        stageA(s0, k3, 1);
        SBAR(); mfc(1, aF, bF); SBAR();
        loadB(s1, 1, bF); loadA(s1, 0, 1, aF);
        stageB(s0, k3);
        SBAR(); mfc(0, aF, bF); SBAR();
        loadA(s1, 1, 1, aF);
        VMCNT(6); SBAR(); mfc(1, aF, bF); SBAR();

        const int ns0 = s2, ns1 = s0, ns2 = s1;
        s0 = ns0; s1 = ns1; s2 = ns2;
    }
    VMCNT(0);

    const int rg = g4 * 4;
    if constexpr (MODE == 0) {
#pragma unroll
        for (int mi = 0; mi < 4; mi++)
#pragma unroll
            for (int ni = 0; ni < 4; ni++) {
                size_t base = (size_t)(m0 + wr * 64 + mi * 16 + rg) * N
                            + (n0 + wc * 64 + ni * 16 + fr);
#pragma unroll
                for (int r = 0; r < 4; r++)
                    store_out(&Cp[base + (size_t)r * N], acc[mi][ni][r]);
            }
    } else {
        __syncthreads();
        short* OT = As;
        const int OP = 264;
#pragma unroll
        for (int mi = 0; mi < 4; mi++)
#pragma unroll
            for (int ni = 0; ni < 4; ni++) {
                s4v pk;
                pk[0] = (short)f2b(acc[mi][ni][0]);
                pk[1] = (short)f2b(acc[mi][ni][1]);
                pk[2] = (short)f2b(acc[mi][ni][2]);
                pk[3] = (short)f2b(acc[mi][ni][3]);
                *(s4v*)&OT[(wc * 64 + ni * 16 + fr) * OP + (wr * 64 + mi * 16 + rg)] = pk;
            }
        __syncthreads();
        const int bb = m0 / Sdim;
        const int sb = m0 % Sdim;
        u16* Vt = (u16*)Cp;
#pragma unroll
        for (int ps = 0; ps < 8; ps++) {
            int idx  = ps * 512 + t;
            int orow = idx >> 5;
            int sc8  = (idx & 31) * 8;
            s8v v = *(const s8v*)&OT[orow * OP + sc8];
            *(s8v*)(Vt + ((size_t)bb * D_MODEL + n0 + orow) * Sdim + sb + sc8) = v;
        }
    }
}

// ---------------------------------------------------------------------------
// Causal flash attention v8 = round-14 v5 with K-fragments read DIRECTLY from
// global (L2-resident; 8 same-(b,h) blocks per XCD share the 512KB K panel)
// instead of LDS-staged. Halves DS-pipe traffic; K reads ride the idle
// TA/L2 pipe in parallel. V stays LDS double-buffered with T14 prefetch.
// Pairing (p, 15-p) = 34 iters/block, 256 blocks. LDS 54 KB.
// ---------------------------------------------------------------------------
#define AKV 64
#define VP  72
#define PP  72

__global__ __launch_bounds__(512) void attn_kernel(
    const u16* __restrict__ Qg, const u16* __restrict__ Kg,
    const u16* __restrict__ Vtg, u16* __restrict__ Og, int S)
{
    // Vbuf 2x[128*VP] 36KB | Ps 8x[16*PP] 18KB; epilogue OL [128][128] 32KB
    // overlays smem start (all loop reads complete before reuse).
    __shared__ short smem[2 * 128 * VP + 8 * 16 * PP];
    short* Vbf = smem;
    short* Psb = smem + 2 * 128 * VP;
    short* OL  = smem;

    const int t    = threadIdx.x;
    const int lane = t & 63;
    const int w    = t >> 6;               // 0..7
    const int fr   = lane & 15;
    const int g4   = lane >> 4;
    const int xfr  = (fr & 7) << 3;

    const int d_ = blockIdx.x;
    const int tt = d_ >> 3;
    const int G  = ((tt & 3) << 3) | (d_ & 7);
    const int p  = tt >> 2;
    const int h  = G & 15;
    const int b  = G >> 4;
    const int ntq = S / 128;               // 16

    const u16* Qb  = Qg + ((size_t)b * S) * D_MODEL + (size_t)h * DK;
    const u16* Kb  = Kg + ((size_t)b * S) * D_MODEL + (size_t)h * DK;
    const u16* Vtb = Vtg + ((size_t)b * D_MODEL + (size_t)h * DK) * S;
    u16*       Ob  = Og + ((size_t)b * S) * D_MODEL + (size_t)h * DK;

    // V staging map (512 threads, 2 chunks each)
    const int vd  = t >> 3;                // 0..63 (+64)
    const int vk8 = (t & 7) * 8;

    const int wq64 = (w >> 2) * 64;
    short* Pw = Psb + w * (16 * PP);

    for (int half = 0; half < 2; half++) {
        const int T   = half ? (ntq - 1 - p) : p;
        const int q0  = T * 128;
        const int nkv = 2 * T + 2;

        s8v qf[4];
#pragma unroll
        for (int ks = 0; ks < 4; ks++)
            qf[ks] = *(const s8v*)(Qb +
                (size_t)(q0 + w * 16 + fr) * D_MODEL + ks * 32 + g4 * 8);

        // V tile 0 -> regs -> LDS
        s8v vreg[2];
#pragma unroll
        for (int c = 0; c < 2; c++)
            vreg[c] = *(const s8v*)(Vtb + (size_t)(vd + 64 * c) * S + vk8);
        __syncthreads();                   // prev half's epilogue reads done
#pragma unroll
        for (int c = 0; c < 2; c++)
            *(s8v*)&Vbf[(vd + 64 * c) * VP + vk8] = vreg[c];
        __syncthreads();

        float m_st = -1e30f, l_st = 0.f;
        f4v accO[8];
#pragma unroll
        for (int df = 0; df < 8; df++) accO[df] = (f4v){0.f, 0.f, 0.f, 0.f};
        const int qg = q0 + w * 16 + fr;

        for (int kt = 0; kt < nkv; kt++) {
            const int  kv0  = kt * AKV;
            const int  buf  = kt & 1;
            const bool last = (kt + 1 == nkv);
            const bool act  = (kv0 <= q0 + wq64);

            // T14: issue next V tile's loads now; publish after compute
            if (!last) {
                const size_t kvn = (size_t)(kt + 1) * AKV;
#pragma unroll
                for (int c = 0; c < 2; c++)
                    vreg[c] = *(const s8v*)(Vtb + (size_t)(vd + 64 * c) * S + kvn + vk8);
            }

            if (act) {
                const u16* Kt = Kb + (size_t)kv0 * D_MODEL;
                f4v sacc[4];
#pragma unroll
                for (int i = 0; i < 4; i++) sacc[i] = (f4v){0.f, 0.f, 0.f, 0.f};
                // S^T = K * Q^T : K-frags straight from global (L2 hit)
#pragma unroll
                for (int ks = 0; ks < 4; ks++) {
                    s8v kfr[4];
#pragma unroll
                    for (int kf = 0; kf < 4; kf++)
                        kfr[kf] = *(const s8v*)(Kt +
                            (size_t)(kf * 16 + fr) * D_MODEL + ks * 32 + g4 * 8);
                    __builtin_amdgcn_s_setprio(1);
#pragma unroll
                    for (int kf = 0; kf < 4; kf++)
                        sacc[kf] = mfma16(kfr[kf], qf[ks], sacc[kf]);
                    __builtin_amdgcn_s_setprio(0);
                }

                if (kv0 == q0 + wq64) {        // diagonal tile for this wave
#pragma unroll
                    for (int kf = 0; kf < 4; kf++)
#pragma unroll
                        for (int r = 0; r < 4; r++)
                            if (kv0 + kf * 16 + g4 * 4 + r > qg)
                                sacc[kf][r] = -1e30f;
                }
                float rm = -1e30f;
#pragma unroll
                for (int kf = 0; kf < 4; kf++)
                    rm = fmaxf(rm, fmaxf(fmaxf(sacc[kf][0], sacc[kf][1]),
                                         fmaxf(sacc[kf][2], sacc[kf][3])));
                rm = fmaxf(rm, __shfl_xor(rm, 16));
                rm = fmaxf(rm, __shfl_xor(rm, 32));
                if (__any(rm > m_st)) {        // exact defer: P <= 1 otherwise
                    float mn   = fmaxf(m_st, rm);
                    float corr = fexp2(m_st - mn);
                    l_st *= corr;
#pragma unroll
                    for (int df = 0; df < 8; df++) {
                        accO[df][0] *= corr; accO[df][1] *= corr;
                        accO[df][2] *= corr; accO[df][3] *= corr;
                    }
                    m_st = mn;
                }
                float rsum = 0.f;
#pragma unroll
                for (int kf = 0; kf < 4; kf++) {
                    float p0 = fexp2(sacc[kf][0] - m_st);
                    float p1 = fexp2(sacc[kf][1] - m_st);
                    float p2 = fexp2(sacc[kf][2] - m_st);
                    float p3 = fexp2(sacc[kf][3] - m_st);
                    rsum += (p0 + p1) + (p2 + p3);
                    s4v pk;
                    pk[0] = (short)f2b(p0); pk[1] = (short)f2b(p1);
                    pk[2] = (short)f2b(p2); pk[3] = (short)f2b(p3);
                    *(s4v*)&Pw[fr * PP + kf * 16 + g4 * 4] = pk;
                }
                rsum += __shfl_xor(rsum, 16);
                rsum += __shfl_xor(rsum, 32);
                l_st += rsum;

                __builtin_amdgcn_s_setprio(1);
#pragma unroll
                for (int ks = 0; ks < 2; ks++) {
                    s8v pf = *(const s8v*)&Pw[fr * PP + ks * 32 + g4 * 8];
#pragma unroll
                    for (int df = 0; df < 8; df++) {
                        s8v vf = *(const s8v*)&Vbf[buf * (128 * VP) +
                                                   (df * 16 + fr) * VP +
                                                   ks * 32 + g4 * 8];
                        accO[df] = mfma16(vf, pf, accO[df]);
                    }
                }
                __builtin_amdgcn_s_setprio(0);
            }

            // publish prefetched V tile to the other buffer
            if (!last) {
#pragma unroll
                for (int c = 0; c < 2; c++)
                    *(s8v*)&Vbf[(buf ^ 1) * (128 * VP) + (vd + 64 * c) * VP + vk8] = vreg[c];
            }
            __syncthreads();
        }

        // normalize, transpose O^T -> O through OL overlay, coalesced store
        float inv = 1.f / l_st;
#pragma unroll
        for (int df = 0; df < 8; df++) {
            s4v ov;
            ov[0] = (short)f2b(accO[df][0] * inv);
            ov[1] = (short)f2b(accO[df][1] * inv);
            ov[2] = (short)f2b(accO[df][2] * inv);
            ov[3] = (short)f2b(accO[df][3] * inv);
            *(s4v*)&OL[(w * 16 + fr) * 128 + ((df * 16 + g4 * 4) ^ xfr)] = ov;
        }
        __syncthreads();
#pragma unroll
        for (int i = 0; i < 4; i++) {
            int row = i * 32 + (t >> 4);
            int ch  = (t & 15) * 8;
            s8v v = *(const s8v*)&OL[row * 128 + (ch ^ ((row & 7) << 3))];
            *(s8v*)(Ob + (size_t)(q0 + row) * D_MODEL + ch) = v;
        }
    }
}

// ---------------------------------------------------------------------------
extern "C" void kernel_launch(void* const* d_in, const int* in_sizes, int n_in,
                              void* d_out, int out_size, void* d_ws, size_t ws_size,
                              hipStream_t stream)
{
    const float* x  = (const float*)d_in[0];
    const float* wq = (const float*)d_in[1];
    const float* wk = (const float*)d_in[2];
    const float* wv = (const float*)d_in[3];
    const float* wo = (const float*)d_in[4];
    const int*   tp = (const int*)d_in[5];

    const int S  = in_sizes[5];
    const int BS = in_sizes[0] / D_MODEL;   // B*S rows (4096)
    const int Bn = BS / S;
    const int NW = D_MODEL * D_MODEL;
    const int NX = BS * D_MODEL;

    // ws (u16 elems): [Q][K][Vt][Xb -> O][Wq][Wk][Wv][Wo][rope tab (1MB)]
    u16* Qw  = (u16*)d_ws;
    u16* Kw  = Qw + (size_t)NX;
    u16* Vw  = Kw + (size_t)NX;
    u16* Xb  = Vw + (size_t)NX;
    u16* Wqb = Xb + (size_t)NX;
    u16* Wkb = Wqb + (size_t)NW;
    u16* Wvb = Wkb + (size_t)NW;
    u16* Wob = Wvb + (size_t)NW;
    float2* Rt = (float2*)(Wob + (size_t)NW);   // S*64 float2 = 1 MB

    {
        dim3 g((NX / 8 + 255) / 256, 5);
        cvt_bf16<<<g, 256, 0, stream>>>(x, wq, wk, wv, wo,
                                        Xb, Wqb, Wkb, Wvb, Wob, NX, NW);
    }

    // RoPE cos/sin table (consumed by gemm256 epilogue)
    rope_table<<<(S * 64 + 255) / 256, 256, 0, stream>>>(Rt, tp, S);

    // Q,K projections with fused RoPE: (16,8,2) = 256 blocks = 1 full round
    dim3 gqk(BS / 256, D_MODEL / 256, 2);
    gemm256<<<gqk, 512, 0, stream>>>(Xb, Wqb, Wkb, Qw, Kw, Rt, S,
                                     BS, D_MODEL, D_MODEL);

    // V projection with fused V^T epilogue: (16,16) = 256 blocks = 1 round
    dim3 gv(BS / 256, D_MODEL / 128, 1);
    gemm128<u16, 1><<<gv, 512, 0, stream>>>(Xb, Wvb, Vw, BS, D_MODEL, D_MODEL, S);

    // causal flash attention v8: O (bf16) into Xb (x dead after V-GEMM)
    attn_kernel<<<dim3((S / 256) * NH * Bn, 1, 1), 512, 0, stream>>>(Qw, Kw, Vw, Xb, S);

    // output projection -> fp32 d_out: (16,16) = 256 blocks = 1 round
    dim3 go(BS / 256, D_MODEL / 128, 1);
    gemm128<float, 0><<<go, 512, 0, stream>>>(Xb, Wob, (float*)d_out,
                                              BS, D_MODEL, D_MODEL, S);
}

// Round 17
// 229.185 us; speedup vs baseline: 1.4093x; 1.4093x over previous
//
#include <hip/hip_runtime.h>
#include <stdint.h>
#include <stddef.h>

typedef unsigned short u16;
typedef unsigned int u32;
typedef __attribute__((ext_vector_type(8))) short s8v;   // 8 bf16 = one MFMA A/B frag
typedef __attribute__((ext_vector_type(4))) short s4v;
typedef __attribute__((ext_vector_type(4))) float f4v;   // MFMA C/D frag / float4

#define D_MODEL 2048
#define NH 16
#define DK 128

__device__ __forceinline__ float b2f(u16 u) {
    union { u32 i; float f; } v; v.i = ((u32)u) << 16; return v.f;
}
__device__ __forceinline__ u16 f2b(float f) {  // RNE; values here always finite
    u32 u = __builtin_bit_cast(u32, f);
    u32 r = (u + 0x7fffu + ((u >> 16) & 1u)) >> 16;
    return (u16)r;
}
__device__ __forceinline__ float fexp2(float x) {        // native v_exp_f32 (base-2)
    return __builtin_amdgcn_exp2f(x);
}
__device__ __forceinline__ f4v mfma16(s8v a, s8v b, f4v c) {
    return __builtin_amdgcn_mfma_f32_16x16x32_bf16(a, b, c, 0, 0, 0);
}
// async global->LDS, 16B/lane. LDS dest must be the WAVE-UNIFORM base; HW adds lane*16.
__device__ __forceinline__ void gload_lds16(const void* g, void* l) {
    __builtin_amdgcn_global_load_lds(
        (const __attribute__((address_space(1))) u32*)(uintptr_t)g,
        (__attribute__((address_space(3))) u32*)(uintptr_t)l, 16, 0, 0);
}

__device__ __forceinline__ void store_out(u16* p, float v)   { *p = f2b(v); }
__device__ __forceinline__ void store_out(float* p, float v) { *p = v; }

#define SBAR()   asm volatile("s_barrier" ::: "memory")
#define VMCNT(n) asm volatile("s_waitcnt vmcnt(" #n ")" ::: "memory")

// ---------------------------------------------------------------------------
// fp32 -> bf16 conversion pass. grid.y selects segment (0: x, 1..4: weights).
// ---------------------------------------------------------------------------
__global__ __launch_bounds__(256) void cvt_bf16(
    const float* __restrict__ s0, const float* __restrict__ s1,
    const float* __restrict__ s2, const float* __restrict__ s3,
    const float* __restrict__ s4,
    u16* __restrict__ d0, u16* __restrict__ d1, u16* __restrict__ d2,
    u16* __restrict__ d3, u16* __restrict__ d4,
    int n0, int nw)
{
    const int seg = blockIdx.y;
    const float* s = (seg == 0) ? s0 : (seg == 1) ? s1 : (seg == 2) ? s2 : (seg == 3) ? s3 : s4;
    u16*         d = (seg == 0) ? d0 : (seg == 1) ? d1 : (seg == 2) ? d2 : (seg == 3) ? d3 : d4;
    const int    n = (seg == 0) ? n0 : nw;
    int i = (blockIdx.x * 256 + threadIdx.x) * 8;
    if (i >= n) return;
    f4v a = *(const f4v*)(s + i);
    f4v b = *(const f4v*)(s + i + 4);
    s8v o;
    o[0] = (short)f2b(a[0]); o[1] = (short)f2b(a[1]);
    o[2] = (short)f2b(a[2]); o[3] = (short)f2b(a[3]);
    o[4] = (short)f2b(b[0]); o[5] = (short)f2b(b[1]);
    o[6] = (short)f2b(b[2]); o[7] = (short)f2b(b[3]);
    *(s8v*)(d + i) = o;
}

// ---------------------------------------------------------------------------
// RoPE cos/sin table: tab[s*64 + ip] = (cos, sin)(pos[s] * 10000^(-ip/64)).
// ---------------------------------------------------------------------------
__global__ __launch_bounds__(256) void rope_table(
    float2* __restrict__ tab, const int* __restrict__ pos, int S)
{
    int idx = blockIdx.x * 256 + threadIdx.x;
    if (idx >= S * 64) return;
    int s  = idx >> 6;
    int ip = idx & 63;
    float freq = __expf((float)ip * -0.14391156831212787f);  // 10000^(-ip/64)
    float ang  = (float)pos[s] * freq;
    tab[idx] = make_float2(cosf(ang), sinf(ang));
}

// ---------------------------------------------------------------------------
// GEMM 8-phase 256x256 (m201 geometry) + fused RoPE epilogue.
// vmcnt: P1/P5 = 4; P4/P8 = 2 (certify the h1-unit staged 1 phase earlier).
// Grid (16,8,2) = 256 blocks = one perfect CU round (Q and K projections).
// ---------------------------------------------------------------------------
__global__ __launch_bounds__(512) void gemm256(
    const u16* __restrict__ A,
    const u16* __restrict__ B0, const u16* __restrict__ B1,
    u16* __restrict__ C0, u16* __restrict__ C1,
    const float2* __restrict__ rtab, int Sdim,
    int M, int N, int K)
{
    const int z = blockIdx.z;
    const u16* Bp = (z == 0) ? B0 : B1;
    u16*       Cp = (z == 0) ? C0 : C1;

    __shared__ short As[2 * 256 * 64];   // 64 KB (2 slots)
    __shared__ short Bs[2 * 256 * 64];   // 64 KB

    const int t    = threadIdx.x;
    const int lane = t & 63;
    const int w    = t >> 6;             // 0..7
    const int wr   = w >> 2;             // 0..1  (128-row band)
    const int wc   = w & 3;              // 0..3  (64-col band)
    const int m0   = blockIdx.x * 256;
    const int n0   = blockIdx.y * 256;

    const int srow = t >> 3;                          // 0..63
    const int scol = (((t & 7) ^ ((t >> 3) & 7)) * 8);

    const u16* gA = A  + (size_t)(m0 + srow) * K + scol;
    const u16* gB = Bp + (size_t)(n0 + srow) * K + scol;
    char* lA = (char*)As + (size_t)w * 1024;          // wave-uniform bases
    char* lB = (char*)Bs + (size_t)w * 1024;
    const size_t rstep = (size_t)64 * K;

    const int fr = lane & 15;
    const int g4 = lane >> 4;
    const int xa = fr & 7;

    f4v acc[8][4];
#pragma unroll
    for (int i = 0; i < 8; i++)
#pragma unroll
        for (int j = 0; j < 4; j++) acc[i][j] = (f4v){0.f, 0.f, 0.f, 0.f};

    auto stageA = [&](int p, int kt, int h) {
        const u16* g = gA + (size_t)kt * 64;
#pragma unroll
        for (int j = 0; j < 2; j++)
            gload_lds16(g + (size_t)(2 * h + j) * rstep,
                        lA + p * 32768 + (2 * h + j) * 8192);
    };
    auto stageB = [&](int p, int kt, int h) {
        const u16* g = gB + (size_t)kt * 64;
#pragma unroll
        for (int j = 0; j < 2; j++)
            gload_lds16(g + (size_t)(2 * h + j) * rstep,
                        lB + p * 32768 + (2 * h + j) * 8192);
    };
    auto loadA = [&](int p, int mh, int ks, s8v* aF) {
        const short* base = As + p * 16384;
        const int sl = ((ks * 4 + g4) ^ xa) * 8;
#pragma unroll
        for (int mi = 0; mi < 4; mi++)
            aF[mi] = *(const s8v*)&base[(wr * 128 + mh * 64 + mi * 16 + fr) * 64 + sl];
    };
    auto loadB = [&](int p, int ks, s8v* bF) {
        const short* base = Bs + p * 16384;
        const int sl = ((ks * 4 + g4) ^ xa) * 8;
#pragma unroll
        for (int ni = 0; ni < 4; ni++)
            bF[ni] = *(const s8v*)&base[(wc * 64 + ni * 16 + fr) * 64 + sl];
    };
    auto mfc = [&](int mh, s8v* aF, s8v* bF) {
        __builtin_amdgcn_s_setprio(1);
#pragma unroll
        for (int mi = 0; mi < 4; mi++)
#pragma unroll
            for (int ni = 0; ni < 4; ni++)
                acc[mh * 4 + mi][ni] = mfma16(aF[mi], bF[ni], acc[mh * 4 + mi][ni]);
        __builtin_amdgcn_s_setprio(0);
    };

    const int NT = K / 64;               // 32
    const int NI = NT / 2;               // 16

    stageB(0, 0, 0); stageB(0, 0, 1); stageA(0, 0, 0); stageA(0, 0, 1);
    stageB(1, 1, 0);
    VMCNT(2);
    SBAR();

    for (int i = 0; i < NI; i++) {
        const int k1 = 2 * i + 1;
        const int k2 = (2 * i + 2 < NT) ? 2 * i + 2 : 0;
        const int k3 = (2 * i + 3 < NT) ? 2 * i + 3 : 1;
        s8v aF[4], bF[4];

        // P1
        loadA(0, 0, 0, aF); loadB(0, 0, bF);
        stageB(1, k1, 1);
        VMCNT(4); SBAR();
        mfc(0, aF, bF);
        SBAR();
        // P2
        loadA(0, 1, 0, aF);
        stageA(1, k1, 0);
        SBAR();
        mfc(1, aF, bF);
        SBAR();
        // P3
        loadA(0, 0, 1, aF); loadB(0, 1, bF);
        stageA(1, k1, 1);
        SBAR();
        mfc(0, aF, bF);
        SBAR();
        // P4 — vmcnt(2): certify A(t1,h1) (P3) for P5-P7
        loadA(0, 1, 1, aF);
        stageB(0, k2, 0);
        VMCNT(2); SBAR();
        mfc(1, aF, bF);
        SBAR();
        // P5
        loadA(1, 0, 0, aF); loadB(1, 0, bF);
        stageB(0, k2, 1);
        VMCNT(4); SBAR();
        mfc(0, aF, bF);
        SBAR();
        // P6
        loadA(1, 1, 0, aF);
        stageA(0, k2, 0);
        SBAR();
        mfc(1, aF, bF);
        SBAR();
        // P7
        loadA(1, 0, 1, aF); loadB(1, 1, bF);
        stageA(0, k2, 1);
        SBAR();
        mfc(0, aF, bF);
        SBAR();
        // P8 — vmcnt(2): certify A(t0+2,h1) (P7) for next P1-P4
        loadA(1, 1, 1, aF);
        stageB(1, k3, 0);
        VMCNT(2); SBAR();
        mfc(1, aF, bF);
        SBAR();
    }
    VMCNT(0);

    // fused-RoPE epilogue
    const int rg = g4 * 4;
    const float scale = (z == 0) ? 0.12751919968793342f : 1.0f;  // log2e/sqrt(128)
    const int srow_b = (m0 % Sdim) + wr * 128;   // 256-row tiles never straddle batch
#pragma unroll
    for (int mit = 0; mit < 8; mit++)
#pragma unroll
        for (int ni = 0; ni < 4; ni++) {
            const int col = n0 + wc * 64 + ni * 16 + fr;
            const int ip  = (col & 127) >> 1;
            const int odd = col & 1;
            size_t base = (size_t)(m0 + wr * 128 + mit * 16 + rg) * N + col;
            const int sr = srow_b + mit * 16 + rg;
#pragma unroll
            for (int r = 0; r < 4; r++) {
                float2 cs = rtab[(size_t)(sr + r) * 64 + ip];
                float v  = acc[mit][ni][r];
                float pv = __shfl_xor(v, 1);                   // partner col^1
                float o  = odd ? (pv * cs.y + v * cs.x)        // e*sin + o*cos
                               : (v * cs.x - pv * cs.y);       // e*cos - o*sin
                Cp[base + (size_t)r * N] = f2b(o * scale);
            }
        }
}

// ---------------------------------------------------------------------------
// GEMM 8-phase 256x128 3-slot (triple-buffered; vmcnt(6) at P4/P8 only).
// MODE 0: direct store. MODE 1: fused V^T epilogue.
// ---------------------------------------------------------------------------
template<typename OutT, int MODE>
__global__ __launch_bounds__(512) void gemm128(
    const u16* __restrict__ A, const u16* __restrict__ Bp,
    OutT* __restrict__ Cp, int M, int N, int K, int Sdim)
{
    __shared__ short As[3 * 256 * 64];   // 96 KB (3 slots; also V^T staging)
    __shared__ short Bs[3 * 128 * 64];   // 48 KB

    const int t    = threadIdx.x;
    const int lane = t & 63;
    const int w    = t >> 6;
    const int wr   = w >> 1;
    const int wc   = w & 1;
    const int m0   = blockIdx.x * 256;
    const int n0   = blockIdx.y * 128;

    const int srow = t >> 3;
    const int scol = (((t & 7) ^ ((t >> 3) & 7)) * 8);

    const u16* gA = A  + (size_t)(m0 + srow) * K + scol;
    const u16* gB = Bp + (size_t)(n0 + srow) * K + scol;
    char* lA = (char*)As + (size_t)w * 1024;
    char* lB = (char*)Bs + (size_t)w * 1024;
    const size_t rstep = (size_t)64 * K;

    const int fr = lane & 15;
    const int g4 = lane >> 4;
    const int xa = fr & 7;

    f4v acc[4][4];
#pragma unroll
    for (int i = 0; i < 4; i++)
#pragma unroll
        for (int j = 0; j < 4; j++) acc[i][j] = (f4v){0.f, 0.f, 0.f, 0.f};

    auto stageA = [&](int p, int kt, int h) {
        const u16* g = gA + (size_t)kt * 64;
#pragma unroll
        for (int j = 0; j < 2; j++)
            gload_lds16(g + (size_t)(2 * h + j) * rstep,
                        lA + p * 32768 + (2 * h + j) * 8192);
    };
    auto stageB = [&](int p, int kt) {
        const u16* g = gB + (size_t)kt * 64;
#pragma unroll
        for (int j = 0; j < 2; j++)
            gload_lds16(g + (size_t)j * rstep,
                        lB + p * 16384 + j * 8192);
    };
    auto loadA = [&](int p, int mh, int ks, s8v* aF) {
        const short* base = As + p * 16384;
        const int sl = ((ks * 4 + g4) ^ xa) * 8;
#pragma unroll
        for (int j = 0; j < 2; j++)
            aF[j] = *(const s8v*)&base[(wr * 64 + (mh * 2 + j) * 16 + fr) * 64 + sl];
    };
    auto loadB = [&](int p, int ks, s8v* bF) {
        const short* base = Bs + p * 8192;
        const int sl = ((ks * 4 + g4) ^ xa) * 8;
#pragma unroll
        for (int ni = 0; ni < 4; ni++)
            bF[ni] = *(const s8v*)&base[(wc * 64 + ni * 16 + fr) * 64 + sl];
    };
    auto mfc = [&](int mh, s8v* aF, s8v* bF) {
        __builtin_amdgcn_s_setprio(1);
#pragma unroll
        for (int j = 0; j < 2; j++)
#pragma unroll
            for (int ni = 0; ni < 4; ni++)
                acc[mh * 2 + j][ni] = mfma16(aF[j], bF[ni], acc[mh * 2 + j][ni]);
        __builtin_amdgcn_s_setprio(0);
    };

    const int NT = K / 64;
    const int NI = NT / 2;

    stageA(0, 0, 0); stageA(0, 0, 1); stageB(0, 0);
    stageA(1, 1, 0); stageA(1, 1, 1); stageB(1, 1);
    VMCNT(6);
    SBAR();

    int s0 = 0, s1 = 1, s2 = 2;
    for (int i = 0; i < NI; i++) {
        const int k2 = (2 * i + 2 < NT) ? 2 * i + 2 : 0;
        const int k3 = (2 * i + 3 < NT) ? 2 * i + 3 : 1;
        s8v aF[2], bF[4];

        loadB(s0, 0, bF); loadA(s0, 0, 0, aF);
        stageA(s2, k2, 0);
        SBAR(); mfc(0, aF, bF); SBAR();
        loadA(s0, 1, 0, aF);
        stageA(s2, k2, 1);
        SBAR(); mfc(1, aF, bF); SBAR();
        loadB(s0, 1, bF); loadA(s0, 0, 1, aF);
        stageB(s2, k2);
        SBAR(); mfc(0, aF, bF); SBAR();
        loadA(s0, 1, 1, aF);
        VMCNT(6); SBAR(); mfc(1, aF, bF); SBAR();
        loadB(s1, 0, bF); loadA(s1, 0, 0, aF);
        stageA(s0, k3, 0);
        SBAR(); mfc(0, aF, bF); SBAR();
        loadA(s1, 1, 0, aF);
        stageA(s0, k3, 1);
        SBAR(); mfc(1, aF, bF); SBAR();
        loadB(s1, 1, bF); loadA(s1, 0, 1, aF);
        stageB(s0, k3);
        SBAR(); mfc(0, aF, bF); SBAR();
        loadA(s1, 1, 1, aF);
        VMCNT(6); SBAR(); mfc(1, aF, bF); SBAR();

        const int ns0 = s2, ns1 = s0, ns2 = s1;
        s0 = ns0; s1 = ns1; s2 = ns2;
    }
    VMCNT(0);

    const int rg = g4 * 4;
    if constexpr (MODE == 0) {
#pragma unroll
        for (int mi = 0; mi < 4; mi++)
#pragma unroll
            for (int ni = 0; ni < 4; ni++) {
                size_t base = (size_t)(m0 + wr * 64 + mi * 16 + rg) * N
                            + (n0 + wc * 64 + ni * 16 + fr);
#pragma unroll
                for (int r = 0; r < 4; r++)
                    store_out(&Cp[base + (size_t)r * N], acc[mi][ni][r]);
            }
    } else {
        __syncthreads();
        short* OT = As;
        const int OP = 264;
#pragma unroll
        for (int mi = 0; mi < 4; mi++)
#pragma unroll
            for (int ni = 0; ni < 4; ni++) {
                s4v pk;
                pk[0] = (short)f2b(acc[mi][ni][0]);
                pk[1] = (short)f2b(acc[mi][ni][1]);
                pk[2] = (short)f2b(acc[mi][ni][2]);
                pk[3] = (short)f2b(acc[mi][ni][3]);
                *(s4v*)&OT[(wc * 64 + ni * 16 + fr) * OP + (wr * 64 + mi * 16 + rg)] = pk;
            }
        __syncthreads();
        const int bb = m0 / Sdim;
        const int sb = m0 % Sdim;
        u16* Vt = (u16*)Cp;
#pragma unroll
        for (int ps = 0; ps < 8; ps++) {
            int idx  = ps * 512 + t;
            int orow = idx >> 5;
            int sc8  = (idx & 31) * 8;
            s8v v = *(const s8v*)&OT[orow * OP + sc8];
            *(s8v*)(Vt + ((size_t)bb * D_MODEL + n0 + orow) * Sdim + sb + sc8) = v;
        }
    }
}

// ---------------------------------------------------------------------------
// Causal flash attention v5 (round-12/14 champion): 8 waves x 16 q, paired
// tiles (p, 15-p) = 34 iters/block, dbuf K/V + T14 prefetch, 1 barrier/iter,
// T5 setprio around MFMA clusters, exp2-domain softmax, diag-only mask.
// ---------------------------------------------------------------------------
#define AKV 64
#define VP  72
#define PP  72

__global__ __launch_bounds__(512) void attn_kernel(
    const u16* __restrict__ Qg, const u16* __restrict__ Kg,
    const u16* __restrict__ Vtg, u16* __restrict__ Og, int S)
{
    __shared__ short Kbuf[2][64 * 128];    // 32 KB (also O[128][128] staging)
    __shared__ short Vbuf[2][128 * VP];    // 36 KB  V^T tiles [d][kv]
    __shared__ short Ps[8][16 * PP];       // 18 KB  per-wave P [q][kv]

    const int t    = threadIdx.x;
    const int lane = t & 63;
    const int w    = t >> 6;               // 0..7
    const int fr   = lane & 15;
    const int g4   = lane >> 4;
    const int xfr  = (fr & 7) << 3;

    const int d_ = blockIdx.x;
    const int tt = d_ >> 3;
    const int G  = ((tt & 3) << 3) | (d_ & 7);
    const int p  = tt >> 2;
    const int h  = G & 15;
    const int b  = G >> 4;
    const int ntq = S / 128;               // 16

    const u16* Qb  = Qg + ((size_t)b * S) * D_MODEL + (size_t)h * DK;
    const u16* Kb  = Kg + ((size_t)b * S) * D_MODEL + (size_t)h * DK;
    const u16* Vtb = Vtg + ((size_t)b * D_MODEL + (size_t)h * DK) * S;
    u16*       Ob  = Og + ((size_t)b * S) * D_MODEL + (size_t)h * DK;

    const int krow = t >> 4;               // 0..31 (+32)
    const int kc8  = (t & 15) * 8;
    const int kxor = (krow & 7) << 3;
    const int vd   = t >> 3;               // 0..63 (+64)
    const int vk8  = (t & 7) * 8;

    const int wq64 = (w >> 2) * 64;

    for (int half = 0; half < 2; half++) {
        const int T   = half ? (ntq - 1 - p) : p;
        const int q0  = T * 128;
        const int nkv = 2 * T + 2;

        s8v qf[4];
#pragma unroll
        for (int ks = 0; ks < 4; ks++)
            qf[ks] = *(const s8v*)(Qb +
                (size_t)(q0 + w * 16 + fr) * D_MODEL + ks * 32 + g4 * 8);

        s8v kreg[2], vreg[2];
#pragma unroll
        for (int c = 0; c < 2; c++) {
            kreg[c] = *(const s8v*)(Kb + (size_t)(krow + 32 * c) * D_MODEL + kc8);
            vreg[c] = *(const s8v*)(Vtb + (size_t)(vd + 64 * c) * S + vk8);
        }
        __syncthreads();
#pragma unroll
        for (int c = 0; c < 2; c++)
            *(s8v*)&Kbuf[0][(krow + 32 * c) * 128 + (kc8 ^ kxor)] = kreg[c];
#pragma unroll
        for (int c = 0; c < 2; c++)
            *(s8v*)&Vbuf[0][(vd + 64 * c) * VP + vk8] = vreg[c];
        __syncthreads();

        float m_st = -1e30f, l_st = 0.f;
        f4v accO[8];
#pragma unroll
        for (int df = 0; df < 8; df++) accO[df] = (f4v){0.f, 0.f, 0.f, 0.f};
        const int qg = q0 + w * 16 + fr;

        for (int kt = 0; kt < nkv; kt++) {
            const int  kv0  = kt * AKV;
            const int  buf  = kt & 1;
            const bool last = (kt + 1 == nkv);
            const bool act  = (kv0 <= q0 + wq64);

            if (!last) {
                const size_t kvn = (size_t)(kt + 1) * AKV;
#pragma unroll
                for (int c = 0; c < 2; c++) {
                    kreg[c] = *(const s8v*)(Kb + (kvn + krow + 32 * c) * D_MODEL + kc8);
                    vreg[c] = *(const s8v*)(Vtb + (size_t)(vd + 64 * c) * S + kvn + vk8);
                }
            }

            if (act) {
                f4v sacc[4];
#pragma unroll
                for (int i = 0; i < 4; i++) sacc[i] = (f4v){0.f, 0.f, 0.f, 0.f};
                __builtin_amdgcn_s_setprio(1);
#pragma unroll
                for (int ks = 0; ks < 4; ks++) {
#pragma unroll
                    for (int kf = 0; kf < 4; kf++) {
                        s8v kfr = *(const s8v*)&Kbuf[buf][(kf * 16 + fr) * 128 +
                                                         ((ks * 32 + g4 * 8) ^ xfr)];
                        sacc[kf] = mfma16(kfr, qf[ks], sacc[kf]);
                    }
                }
                __builtin_amdgcn_s_setprio(0);

                if (kv0 == q0 + wq64) {
#pragma unroll
                    for (int kf = 0; kf < 4; kf++)
#pragma unroll
                        for (int r = 0; r < 4; r++)
                            if (kv0 + kf * 16 + g4 * 4 + r > qg)
                                sacc[kf][r] = -1e30f;
                }
                float rm = -1e30f;
#pragma unroll
                for (int kf = 0; kf < 4; kf++)
                    rm = fmaxf(rm, fmaxf(fmaxf(sacc[kf][0], sacc[kf][1]),
                                         fmaxf(sacc[kf][2], sacc[kf][3])));
                rm = fmaxf(rm, __shfl_xor(rm, 16));
                rm = fmaxf(rm, __shfl_xor(rm, 32));
                if (__any(rm > m_st)) {
                    float mn   = fmaxf(m_st, rm);
                    float corr = fexp2(m_st - mn);
                    l_st *= corr;
#pragma unroll
                    for (int df = 0; df < 8; df++) {
                        accO[df][0] *= corr; accO[df][1] *= corr;
                        accO[df][2] *= corr; accO[df][3] *= corr;
                    }
                    m_st = mn;
                }
                float rsum = 0.f;
#pragma unroll
                for (int kf = 0; kf < 4; kf++) {
                    float p0 = fexp2(sacc[kf][0] - m_st);
                    float p1 = fexp2(sacc[kf][1] - m_st);
                    float p2 = fexp2(sacc[kf][2] - m_st);
                    float p3 = fexp2(sacc[kf][3] - m_st);
                    rsum += (p0 + p1) + (p2 + p3);
                    s4v pk;
                    pk[0] = (short)f2b(p0); pk[1] = (short)f2b(p1);
                    pk[2] = (short)f2b(p2); pk[3] = (short)f2b(p3);
                    *(s4v*)&Ps[w][fr * PP + kf * 16 + g4 * 4] = pk;
                }
                rsum += __shfl_xor(rsum, 16);
                rsum += __shfl_xor(rsum, 32);
                l_st += rsum;

                __builtin_amdgcn_s_setprio(1);
#pragma unroll
                for (int ks = 0; ks < 2; ks++) {
                    s8v pf = *(const s8v*)&Ps[w][fr * PP + ks * 32 + g4 * 8];
#pragma unroll
                    for (int df = 0; df < 8; df++) {
                        s8v vf = *(const s8v*)&Vbuf[buf][(df * 16 + fr) * VP +
                                                         ks * 32 + g4 * 8];
                        accO[df] = mfma16(vf, pf, accO[df]);
                    }
                }
                __builtin_amdgcn_s_setprio(0);
            }

            if (!last) {
#pragma unroll
                for (int c = 0; c < 2; c++)
                    *(s8v*)&Kbuf[buf ^ 1][(krow + 32 * c) * 128 + (kc8 ^ kxor)] = kreg[c];
#pragma unroll
                for (int c = 0; c < 2; c++)
                    *(s8v*)&Vbuf[buf ^ 1][(vd + 64 * c) * VP + vk8] = vreg[c];
            }
            __syncthreads();
        }

        float inv = 1.f / l_st;
        short* OL = (short*)&Kbuf[0][0];
#pragma unroll
        for (int df = 0; df < 8; df++) {
            s4v ov;
            ov[0] = (short)f2b(accO[df][0] * inv);
            ov[1] = (short)f2b(accO[df][1] * inv);
            ov[2] = (short)f2b(accO[df][2] * inv);
            ov[3] = (short)f2b(accO[df][3] * inv);
            *(s4v*)&OL[(w * 16 + fr) * 128 + ((df * 16 + g4 * 4) ^ xfr)] = ov;
        }
        __syncthreads();
#pragma unroll
        for (int i = 0; i < 4; i++) {
            int row = i * 32 + (t >> 4);
            int ch  = (t & 15) * 8;
            s8v v = *(const s8v*)&OL[row * 128 + (ch ^ ((row & 7) << 3))];
            *(s8v*)(Ob + (size_t)(q0 + row) * D_MODEL + ch) = v;
        }
    }
}

// ---------------------------------------------------------------------------
extern "C" void kernel_launch(void* const* d_in, const int* in_sizes, int n_in,
                              void* d_out, int out_size, void* d_ws, size_t ws_size,
                              hipStream_t stream)
{
    const float* x  = (const float*)d_in[0];
    const float* wq = (const float*)d_in[1];
    const float* wk = (const float*)d_in[2];
    const float* wv = (const float*)d_in[3];
    const float* wo = (const float*)d_in[4];
    const int*   tp = (const int*)d_in[5];

    const int S  = in_sizes[5];
    const int BS = in_sizes[0] / D_MODEL;   // B*S rows (4096)
    const int Bn = BS / S;
    const int NW = D_MODEL * D_MODEL;
    const int NX = BS * D_MODEL;

    // ws (u16 elems): [Q][K][Vt][Xb -> O][Wq][Wk][Wv][Wo][rope tab (1MB)]
    u16* Qw  = (u16*)d_ws;
    u16* Kw  = Qw + (size_t)NX;
    u16* Vw  = Kw + (size_t)NX;
    u16* Xb  = Vw + (size_t)NX;
    u16* Wqb = Xb + (size_t)NX;
    u16* Wkb = Wqb + (size_t)NW;
    u16* Wvb = Wkb + (size_t)NW;
    u16* Wob = Wvb + (size_t)NW;
    float2* Rt = (float2*)(Wob + (size_t)NW);   // S*64 float2 = 1 MB

    {
        dim3 g((NX / 8 + 255) / 256, 5);
        cvt_bf16<<<g, 256, 0, stream>>>(x, wq, wk, wv, wo,
                                        Xb, Wqb, Wkb, Wvb, Wob, NX, NW);
    }

    // RoPE cos/sin table (consumed by gemm256 epilogue)
    rope_table<<<(S * 64 + 255) / 256, 256, 0, stream>>>(Rt, tp, S);

    // Q,K projections with fused RoPE: (16,8,2) = 256 blocks = 1 full round
    dim3 gqk(BS / 256, D_MODEL / 256, 2);
    gemm256<<<gqk, 512, 0, stream>>>(Xb, Wqb, Wkb, Qw, Kw, Rt, S,
                                     BS, D_MODEL, D_MODEL);

    // V projection with fused V^T epilogue: (16,16) = 256 blocks = 1 round
    dim3 gv(BS / 256, D_MODEL / 128, 1);
    gemm128<u16, 1><<<gv, 512, 0, stream>>>(Xb, Wvb, Vw, BS, D_MODEL, D_MODEL, S);

    // causal flash attention v5: O (bf16) into Xb (x dead after V-GEMM)
    attn_kernel<<<dim3((S / 256) * NH * Bn, 1, 1), 512, 0, stream>>>(Qw, Kw, Vw, Xb, S);

    // output projection -> fp32 d_out: (16,16) = 256 blocks = 1 round
    dim3 go(BS / 256, D_MODEL / 128, 1);
    gemm128<float, 0><<<go, 512, 0, stream>>>(Xb, Wob, (float*)d_out,
                                              BS, D_MODEL, D_MODEL, S);
}